// Round 5
// baseline (4056.933 us; speedup 1.0000x reference)
//
#include <hip/hip_runtime.h>
#include <hip/hip_bf16.h>

typedef __attribute__((ext_vector_type(8))) short bf16x8;
typedef __attribute__((ext_vector_type(4))) float f32x4;

#define L_SEQ 128
#define BATCH 64
#define HID   1024
#define GATES 4096
#define NWG   256   // scan workgroups (1 per CU, cooperative)
#define UPW   4     // hidden units per scan WG
#define FSTR  32    // flag padding stride in u32 (128 B line)

#define FENCE_REL_AGENT() __builtin_amdgcn_fence(__ATOMIC_RELEASE, "agent")
#define FENCE_ACQ_AGENT() __builtin_amdgcn_fence(__ATOMIC_ACQUIRE, "agent")

__device__ inline short f2bf_s(float f) {
  __hip_bfloat16 h = __float2bfloat16(f);
  union { __hip_bfloat16 hh; short s; } u; u.hh = h; return u.s;
}
__device__ inline float sigm(float x) { return 1.f / (1.f + __expf(-x)); }
__device__ inline float tanh_f(float x) {
  x = fminf(x, 15.f);                 // avoid inf/inf NaN
  float e = __expf(2.f * x);
  return (e - 1.f) / (e + 1.f);
}

// ---------------- init: h_bf[0] <- hidden, x_bf <- x, bias2, zero barrier ----
__global__ void k_init(const float* __restrict__ hidden, const float* __restrict__ x,
                       const float* __restrict__ bih, const float* __restrict__ bhh,
                       __hip_bfloat16* __restrict__ h_bf0, __hip_bfloat16* __restrict__ x_bf,
                       float* __restrict__ bias2, unsigned* __restrict__ bar) {
  int gid = blockIdx.x * 256 + threadIdx.x;            // 65536 threads
  if (gid < BATCH * HID) h_bf0[gid] = __float2bfloat16(hidden[gid]);
  if (gid < BATCH * 512) x_bf[gid]  = __float2bfloat16(x[gid]);
  if (gid < GATES)       bias2[gid] = bih[gid] + bhh[gid];
  if (gid < 16384)       bar[gid] = 0u;                // flags (256*32) + gen (32*32)
}

// ---------------- split W_ih into bf16 Wx (4096x512) and Wa (4096x512) -------
__global__ void k_wsplit(const float* __restrict__ Wih,
                         __hip_bfloat16* __restrict__ Wx, __hip_bfloat16* __restrict__ Wa) {
  int e = blockIdx.x * 256 + threadIdx.x;              // 4096*128
  int g = e >> 7;
  int ko = (e & 127) << 3;
  const float* src = Wih + (size_t)g * 1024 + ko;
  float4 f0 = *(const float4*)(src);
  float4 f1 = *(const float4*)(src + 4);
  union { bf16x8 v; short s[8]; } o;
  o.s[0]=f2bf_s(f0.x); o.s[1]=f2bf_s(f0.y); o.s[2]=f2bf_s(f0.z); o.s[3]=f2bf_s(f0.w);
  o.s[4]=f2bf_s(f1.x); o.s[5]=f2bf_s(f1.y); o.s[6]=f2bf_s(f1.z); o.s[7]=f2bf_s(f1.w);
  if (ko < 512) *(bf16x8*)(Wx + (size_t)g * 512 + ko)        = o.v;
  else          *(bf16x8*)(Wa + (size_t)g * 512 + (ko - 512)) = o.v;
}

// ---------------- act[l*64+b][512] = rule_emb[r]*v + tok_emb[t]*v (bf16) -----
__global__ void k_act(const int* __restrict__ pa, const float* __restrict__ remb,
                      const float* __restrict__ temb, __hip_bfloat16* __restrict__ act) {
  int row = blockIdx.x;                                // 8192 = l*64+b
  int tid = threadIdx.x;                               // 64
  int r  = pa[row * 3 + 0];
  int tk = pa[row * 3 + 1];
  float sr = (r  != -1) ? 1.f : 0.f; int ri = (r  != -1) ? r  : 0;
  float st = (tk != -1) ? 1.f : 0.f; int ti = (tk != -1) ? tk : 0;
  const float4* rr = (const float4*)(remb + (size_t)ri * 512);
  const float4* tr = (const float4*)(temb + (size_t)ti * 512);
  float4 a = rr[tid * 2], b4 = rr[tid * 2 + 1];
  float4 c4 = tr[tid * 2], d4 = tr[tid * 2 + 1];
  union { bf16x8 v; short s[8]; } o;
  o.s[0]=f2bf_s(sr*a.x + st*c4.x);  o.s[1]=f2bf_s(sr*a.y + st*c4.y);
  o.s[2]=f2bf_s(sr*a.z + st*c4.z);  o.s[3]=f2bf_s(sr*a.w + st*c4.w);
  o.s[4]=f2bf_s(sr*b4.x + st*d4.x); o.s[5]=f2bf_s(sr*b4.y + st*d4.y);
  o.s[6]=f2bf_s(sr*b4.z + st*d4.z); o.s[7]=f2bf_s(sr*b4.w + st*d4.w);
  *(bf16x8*)(act + (size_t)row * 512 + tid * 8) = o.v;
}

// ---------------- bf16 MFMA GEMM: C[m,n] = A[m,:]·B[n,:] + addend ------------
// MODE 0: Cf (fp32) = A@B^T + bias2[n]           (y0: M=64)
// MODE 1: Cb (bf16) = A@B^T + y0[m&63][n]        (xg: M=8192)
template<int MODE>
__global__ __launch_bounds__(256) void k_gemm(
    const __hip_bfloat16* __restrict__ A, const __hip_bfloat16* __restrict__ B,
    const float* __restrict__ addend, float* __restrict__ Cf,
    __hip_bfloat16* __restrict__ Cb, int M) {
  __shared__ __hip_bfloat16 At[128][72];   // +8 pad -> 2-way (free) LDS access
  __shared__ __hip_bfloat16 Bt[128][72];
  const int tid = threadIdx.x;
  const int m0 = blockIdx.y * 128, n0 = blockIdx.x * 128;
  const int w = tid >> 6, lane = tid & 63;
  const int wm = (w >> 1) * 64, wn = (w & 1) * 64;
  const int lm = lane & 15, quad = lane >> 4;
  const int srow = tid >> 1, shalf = (tid & 1) * 32;
  f32x4 acc[4][4] = {};
  for (int k0 = 0; k0 < 512; k0 += 64) {
    int arow = m0 + srow;
    if (MODE == 0 && arow >= M) arow = M - 1;          // clamp (stores guarded)
    const bf16x8* ag = (const bf16x8*)(A + (size_t)arow * 512 + k0 + shalf);
    const bf16x8* bg = (const bf16x8*)(B + (size_t)(n0 + srow) * 512 + k0 + shalf);
    bf16x8 av[4], bv[4];
#pragma unroll
    for (int q = 0; q < 4; ++q) { av[q] = ag[q]; bv[q] = bg[q]; }
    __syncthreads();
#pragma unroll
    for (int q = 0; q < 4; ++q) {
      *(bf16x8*)(&At[srow][shalf + q * 8]) = av[q];
      *(bf16x8*)(&Bt[srow][shalf + q * 8]) = bv[q];
    }
    __syncthreads();
#pragma unroll
    for (int ks = 0; ks < 2; ++ks) {
      bf16x8 af[4], bf[4];
#pragma unroll
      for (int i = 0; i < 4; ++i) {
        af[i] = *(const bf16x8*)(&At[wm + i * 16 + lm][ks * 32 + quad * 8]);
        bf[i] = *(const bf16x8*)(&Bt[wn + i * 16 + lm][ks * 32 + quad * 8]);
      }
#pragma unroll
      for (int i = 0; i < 4; ++i)
#pragma unroll
        for (int j = 0; j < 4; ++j)
          acc[i][j] = __builtin_amdgcn_mfma_f32_16x16x32_bf16(af[i], bf[j], acc[i][j], 0, 0, 0);
    }
  }
  // C/D layout: col = lane&15, row = quad*4 + reg  (m89-verified)
#pragma unroll
  for (int i = 0; i < 4; ++i) {
    int mrow = m0 + wm + i * 16 + quad * 4;
#pragma unroll
    for (int j = 0; j < 4; ++j) {
      int ncol = n0 + wn + j * 16 + lm;
#pragma unroll
      for (int r = 0; r < 4; ++r) {
        int m = mrow + r;
        if (MODE == 0) {
          if (m < M) Cf[(size_t)m * GATES + ncol] = acc[i][j][r] + addend[ncol];
        } else {
          float v = acc[i][j][r] + addend[(size_t)(m & 63) * GATES + ncol];
          Cb[(size_t)m * GATES + ncol] = __float2bfloat16(v);
        }
      }
    }
  }
}

// ---------------- persistent LSTM scan (cooperative, custom grid barrier) ----
// v4: NONTEMPORAL stores for all cross-step/output data (out_hs, hdst,
// out_hn/cn). Each WG writes only 16B per 128B line of out_hs (8 WGs on up to
// 8 XCDs share a line) -> normal stores caused write-allocate line fetches
// (most of the 339 MB FETCH_SIZE) serialized before each release fence. nt =
// no-allocate streaming store: no RFO fetch, nothing dirty for wbl2 to walk.
__global__ __launch_bounds__(256, 1) void k_scan(
    const float* __restrict__ Whh, const __hip_bfloat16* __restrict__ xg,
    const float* __restrict__ state_in, __hip_bfloat16* __restrict__ h_bf,
    float* __restrict__ out_hs, float* __restrict__ out_hn, float* __restrict__ out_cn,
    unsigned* __restrict__ bar) {
  __shared__ __hip_bfloat16 Wl[16 * 1032];   // 16 slice rows [i4,f4,g4,o4], +8 pad
  __shared__ float gl[64 * 17];              // 64 batches x 16 slice cols (+1 pad)
  const int tid = threadIdx.x;
  const int wg = blockIdx.x;
  const int u0 = wg * UPW;
  // W_hh slice -> LDS bf16 (once; reused for all 128 steps)
  for (int e = tid; e < 16 * 128; e += 256) {
    int j = e >> 7;
    int ko = (e & 127) << 3;
    int gate = j >> 2, uu = j & 3;
    const float* src = Whh + (size_t)(gate * HID + u0 + uu) * HID + ko;
    float4 f0 = *(const float4*)(src);
    float4 f1 = *(const float4*)(src + 4);
    union { bf16x8 v; short s[8]; } o;
    o.s[0]=f2bf_s(f0.x); o.s[1]=f2bf_s(f0.y); o.s[2]=f2bf_s(f0.z); o.s[3]=f2bf_s(f0.w);
    o.s[4]=f2bf_s(f1.x); o.s[5]=f2bf_s(f1.y); o.s[6]=f2bf_s(f1.z); o.s[7]=f2bf_s(f1.w);
    *(bf16x8*)(&Wl[j * 1032 + ko]) = o.v;
  }
  const int b = tid >> 2, u = tid & 3;       // this thread's (batch, unit) item
  float c = state_in[b * HID + u0 + u];      // c-state lives in a register
  const int w = tid >> 6, lane = tid & 63;
  const int lm = lane & 15, quad = lane >> 4;
  const int m0 = w * 16;                     // wave's batch tile
  unsigned* flags = bar;                     // flags[wg*FSTR]
  unsigned* gen = bar + NWG * FSTR;          // gen[line*FSTR], line = wg & 31
  // xg for t=0 (software-pipelined: t+1 loads issue before each grid barrier)
  const __hip_bfloat16* xgp0 = xg + (size_t)b * GATES + u0 + u;
  float xi  = __bfloat162float(xgp0[0]);
  float xf  = __bfloat162float(xgp0[1024]);
  float xgg = __bfloat162float(xgp0[2048]);
  float xo  = __bfloat162float(xgp0[3072]);
  __syncthreads();
  for (int t = 0; t < L_SEQ; ++t) {
    const __hip_bfloat16* hsrc = h_bf + (size_t)(t & 1) * (BATCH * HID);
    __hip_bfloat16* hdst = h_bf + (size_t)((t + 1) & 1) * (BATCH * HID);
    // A (= h) fragments: force 32 outstanding 16B loads per lane
    const bf16x8* arow = (const bf16x8*)(hsrc + (m0 + lm) * HID + quad * 8);
    bf16x8 areg[32];
#pragma unroll
    for (int kq = 0; kq < 32; ++kq) areg[kq] = arow[kq * 4];
    __builtin_amdgcn_sched_barrier(0);       // loads stay ABOVE all MFMAs
    f32x4 acc = {0.f, 0.f, 0.f, 0.f};
#pragma unroll
    for (int kq = 0; kq < 32; ++kq) {
      bf16x8 bfrag = *(const bf16x8*)(&Wl[lm * 1032 + kq * 32 + quad * 8]);
      acc = __builtin_amdgcn_mfma_f32_16x16x32_bf16(areg[kq], bfrag, acc, 0, 0, 0);
    }
#pragma unroll
    for (int r = 0; r < 4; ++r) gl[(m0 + quad * 4 + r) * 17 + lm] = acc[r];
    __syncthreads();
    float gi = gl[b * 17 + u]      + xi;
    float gf = gl[b * 17 + 4 + u]  + xf;
    float gg = gl[b * 17 + 8 + u]  + xgg;
    float go = gl[b * 17 + 12 + u] + xo;
    float iv = sigm(gi), fv = sigm(gf), ov = sigm(go), gv = tanh_f(gg);
    c = fv * c + iv * gv;
    float h = ov * tanh_f(c);
    // nt streaming stores: no write-allocate, no false-sharing RFO
    __builtin_nontemporal_store(h, &out_hs[((size_t)t * BATCH + b) * HID + u0 + u]);
    __builtin_nontemporal_store(f2bf_s(h), (short*)hdst + (size_t)b * HID + u0 + u);
    if (t == L_SEQ - 1) {
      __builtin_nontemporal_store(h, &out_hn[(size_t)b * HID + u0 + u]);
      __builtin_nontemporal_store(c, &out_cn[(size_t)b * HID + u0 + u]);
    } else {
      // prefetch xg for t+1; completes during the fence's vmcnt drain
      const __hip_bfloat16* xgp = xg + ((size_t)(t + 1) * BATCH + b) * GATES + u0 + u;
      float nxi  = __bfloat162float(xgp[0]);
      float nxf  = __bfloat162float(xgp[1024]);
      float nxgg = __bfloat162float(xgp[2048]);
      float nxo  = __bfloat162float(xgp[3072]);
      unsigned target = (unsigned)(t + 1);
      // publish this WG's hdst writes, then signal with RELAXED stores only.
      FENCE_REL_AGENT();
      __syncthreads();
      if (wg == 0) {
        if (tid > 0 && tid < NWG) {
          while (__hip_atomic_load(&flags[tid * FSTR], __ATOMIC_RELAXED,
                                   __HIP_MEMORY_SCOPE_AGENT) < target)
            __builtin_amdgcn_s_sleep(1);
        }
        __syncthreads();
        FENCE_ACQ_AGENT();
        if (tid < 32) {
          FENCE_REL_AGENT();
          __hip_atomic_store(&gen[tid * FSTR], target, __ATOMIC_RELAXED,
                             __HIP_MEMORY_SCOPE_AGENT);
        }
      } else {
        if (tid == 0) {
          __hip_atomic_store(&flags[wg * FSTR], target, __ATOMIC_RELAXED,
                             __HIP_MEMORY_SCOPE_AGENT);
          while (__hip_atomic_load(&gen[(wg & 31) * FSTR], __ATOMIC_RELAXED,
                                   __HIP_MEMORY_SCOPE_AGENT) < target)
            __builtin_amdgcn_s_sleep(1);
        }
        __syncthreads();
        FENCE_ACQ_AGENT();
      }
      xi = nxi; xf = nxf; xgg = nxgg; xo = nxo;
    }
  }
}

extern "C" void kernel_launch(void* const* d_in, const int* in_sizes, int n_in,
                              void* d_out, int out_size, void* d_ws, size_t ws_size,
                              hipStream_t stream) {
  const float* x      = (const float*)d_in[0];
  const int*   pa     = (const int*)d_in[1];
  // d_in[2] = mask (unused by reference)
  const float* hidden = (const float*)d_in[3];
  const float* state  = (const float*)d_in[4];
  const float* remb   = (const float*)d_in[5];
  const float* temb   = (const float*)d_in[6];
  const float* Wih    = (const float*)d_in[7];
  const float* Whh    = (const float*)d_in[8];
  const float* bih    = (const float*)d_in[9];
  const float* bhh    = (const float*)d_in[10];

  char* ws = (char*)d_ws;
  size_t off = 0;
  auto take = [&](size_t bytes) { char* p = ws + off; off += (bytes + 255) & ~(size_t)255; return p; };
  unsigned* bar        = (unsigned*)take(16384 * 4);   // padded flags + gen lines
  __hip_bfloat16* h_bf = (__hip_bfloat16*)take((size_t)2 * BATCH * HID * 2);
  __hip_bfloat16* x_bf = (__hip_bfloat16*)take((size_t)BATCH * 512 * 2);
  float* bias2         = (float*)take((size_t)GATES * 4);
  __hip_bfloat16* Wx   = (__hip_bfloat16*)take((size_t)GATES * 512 * 2);
  __hip_bfloat16* Wa   = (__hip_bfloat16*)take((size_t)GATES * 512 * 2);
  __hip_bfloat16* act  = (__hip_bfloat16*)take((size_t)8192 * 512 * 2);
  float* y0            = (float*)take((size_t)BATCH * GATES * 4);
  __hip_bfloat16* xg   = (__hip_bfloat16*)take((size_t)8192 * GATES * 2);  // ~81 MB total

  float* out_hs = (float*)d_out;
  float* out_hn = out_hs + (size_t)L_SEQ * BATCH * HID;
  float* out_cn = out_hn + (size_t)BATCH * HID;

  hipLaunchKernelGGL(k_init, dim3(256), dim3(256), 0, stream, hidden, x, bih, bhh, h_bf, x_bf, bias2, bar);
  hipLaunchKernelGGL(k_wsplit, dim3(2048), dim3(256), 0, stream, Wih, Wx, Wa);
  hipLaunchKernelGGL(k_act, dim3(8192), dim3(64), 0, stream, pa, remb, temb, act);
  hipLaunchKernelGGL((k_gemm<0>), dim3(32, 1), dim3(256), 0, stream,
                     x_bf, Wx, bias2, y0, (__hip_bfloat16*)nullptr, 64);
  hipLaunchKernelGGL((k_gemm<1>), dim3(32, 64), dim3(256), 0, stream,
                     act, Wa, y0, (float*)nullptr, xg, 8192);
  void* args[] = { (void*)&Whh, (void*)&xg, (void*)&state, (void*)&h_bf,
                   (void*)&out_hs, (void*)&out_hn, (void*)&out_cn, (void*)&bar };
  (void)hipLaunchCooperativeKernel((void*)k_scan, dim3(NWG), dim3(256), args, 0, stream);
}

// Round 6
// 1124.802 us; speedup vs baseline: 3.6068x; 3.6068x over previous
//
#include <hip/hip_runtime.h>
#include <hip/hip_bf16.h>

typedef __attribute__((ext_vector_type(8))) short bf16x8;
typedef __attribute__((ext_vector_type(4))) float f32x4;

#define L_SEQ 128
#define BATCH 64
#define HID   1024
#define GATES 4096
#define NWG   256   // scan workgroups (1 per CU, cooperative)
#define UPW   4     // hidden units per scan WG
#define FSTR  32    // flag padding stride in u32 (128 B line)

__device__ inline short f2bf_s(float f) {
  __hip_bfloat16 h = __float2bfloat16(f);
  union { __hip_bfloat16 hh; short s; } u; u.hh = h; return u.s;
}
__device__ inline float sigm(float x) { return 1.f / (1.f + __expf(-x)); }
__device__ inline float tanh_f(float x) {
  x = fminf(x, 15.f);                 // avoid inf/inf NaN
  float e = __expf(2.f * x);
  return (e - 1.f) / (e + 1.f);
}

// ---------------- init: h_all[0] <- hidden, x_bf <- x, bias2, zero barrier ---
__global__ void k_init(const float* __restrict__ hidden, const float* __restrict__ x,
                       const float* __restrict__ bih, const float* __restrict__ bhh,
                       __hip_bfloat16* __restrict__ h_all0, __hip_bfloat16* __restrict__ x_bf,
                       float* __restrict__ bias2, unsigned* __restrict__ bar) {
  int gid = blockIdx.x * 256 + threadIdx.x;            // 65536 threads
  if (gid < BATCH * HID) h_all0[gid] = __float2bfloat16(hidden[gid]);
  if (gid < BATCH * 512) x_bf[gid]  = __float2bfloat16(x[gid]);
  if (gid < GATES)       bias2[gid] = bih[gid] + bhh[gid];
  if (gid < 16384)       bar[gid] = 0u;                // flags (256*32) + gen (32*32)
}

// ---------------- split W_ih into bf16 Wx (4096x512) and Wa (4096x512) -------
__global__ void k_wsplit(const float* __restrict__ Wih,
                         __hip_bfloat16* __restrict__ Wx, __hip_bfloat16* __restrict__ Wa) {
  int e = blockIdx.x * 256 + threadIdx.x;              // 4096*128
  int g = e >> 7;
  int ko = (e & 127) << 3;
  const float* src = Wih + (size_t)g * 1024 + ko;
  float4 f0 = *(const float4*)(src);
  float4 f1 = *(const float4*)(src + 4);
  union { bf16x8 v; short s[8]; } o;
  o.s[0]=f2bf_s(f0.x); o.s[1]=f2bf_s(f0.y); o.s[2]=f2bf_s(f0.z); o.s[3]=f2bf_s(f0.w);
  o.s[4]=f2bf_s(f1.x); o.s[5]=f2bf_s(f1.y); o.s[6]=f2bf_s(f1.z); o.s[7]=f2bf_s(f1.w);
  if (ko < 512) *(bf16x8*)(Wx + (size_t)g * 512 + ko)        = o.v;
  else          *(bf16x8*)(Wa + (size_t)g * 512 + (ko - 512)) = o.v;
}

// ---------------- act[l*64+b][512] = rule_emb[r]*v + tok_emb[t]*v (bf16) -----
__global__ void k_act(const int* __restrict__ pa, const float* __restrict__ remb,
                      const float* __restrict__ temb, __hip_bfloat16* __restrict__ act) {
  int row = blockIdx.x;                                // 8192 = l*64+b
  int tid = threadIdx.x;                               // 64
  int r  = pa[row * 3 + 0];
  int tk = pa[row * 3 + 1];
  float sr = (r  != -1) ? 1.f : 0.f; int ri = (r  != -1) ? r  : 0;
  float st = (tk != -1) ? 1.f : 0.f; int ti = (tk != -1) ? tk : 0;
  const float4* rr = (const float4*)(remb + (size_t)ri * 512);
  const float4* tr = (const float4*)(temb + (size_t)ti * 512);
  float4 a = rr[tid * 2], b4 = rr[tid * 2 + 1];
  float4 c4 = tr[tid * 2], d4 = tr[tid * 2 + 1];
  union { bf16x8 v; short s[8]; } o;
  o.s[0]=f2bf_s(sr*a.x + st*c4.x);  o.s[1]=f2bf_s(sr*a.y + st*c4.y);
  o.s[2]=f2bf_s(sr*a.z + st*c4.z);  o.s[3]=f2bf_s(sr*a.w + st*c4.w);
  o.s[4]=f2bf_s(sr*b4.x + st*d4.x); o.s[5]=f2bf_s(sr*b4.y + st*d4.y);
  o.s[6]=f2bf_s(sr*b4.z + st*d4.z); o.s[7]=f2bf_s(sr*b4.w + st*d4.w);
  *(bf16x8*)(act + (size_t)row * 512 + tid * 8) = o.v;
}

// ---------------- bf16 MFMA GEMM: C[m,n] = A[m,:]·B[n,:] + addend ------------
// MODE 0: Cf (fp32) = A@B^T + bias2[n]           (y0: M=64)
// MODE 1: Cb (bf16) = A@B^T + y0[m&63][n]        (xg: M=8192)
template<int MODE>
__global__ __launch_bounds__(256) void k_gemm(
    const __hip_bfloat16* __restrict__ A, const __hip_bfloat16* __restrict__ B,
    const float* __restrict__ addend, float* __restrict__ Cf,
    __hip_bfloat16* __restrict__ Cb, int M) {
  __shared__ __hip_bfloat16 At[128][72];   // +8 pad -> 2-way (free) LDS access
  __shared__ __hip_bfloat16 Bt[128][72];
  const int tid = threadIdx.x;
  const int m0 = blockIdx.y * 128, n0 = blockIdx.x * 128;
  const int w = tid >> 6, lane = tid & 63;
  const int wm = (w >> 1) * 64, wn = (w & 1) * 64;
  const int lm = lane & 15, quad = lane >> 4;
  const int srow = tid >> 1, shalf = (tid & 1) * 32;
  f32x4 acc[4][4] = {};
  for (int k0 = 0; k0 < 512; k0 += 64) {
    int arow = m0 + srow;
    if (MODE == 0 && arow >= M) arow = M - 1;          // clamp (stores guarded)
    const bf16x8* ag = (const bf16x8*)(A + (size_t)arow * 512 + k0 + shalf);
    const bf16x8* bg = (const bf16x8*)(B + (size_t)(n0 + srow) * 512 + k0 + shalf);
    bf16x8 av[4], bv[4];
#pragma unroll
    for (int q = 0; q < 4; ++q) { av[q] = ag[q]; bv[q] = bg[q]; }
    __syncthreads();
#pragma unroll
    for (int q = 0; q < 4; ++q) {
      *(bf16x8*)(&At[srow][shalf + q * 8]) = av[q];
      *(bf16x8*)(&Bt[srow][shalf + q * 8]) = bv[q];
    }
    __syncthreads();
#pragma unroll
    for (int ks = 0; ks < 2; ++ks) {
      bf16x8 af[4], bf[4];
#pragma unroll
      for (int i = 0; i < 4; ++i) {
        af[i] = *(const bf16x8*)(&At[wm + i * 16 + lm][ks * 32 + quad * 8]);
        bf[i] = *(const bf16x8*)(&Bt[wn + i * 16 + lm][ks * 32 + quad * 8]);
      }
#pragma unroll
      for (int i = 0; i < 4; ++i)
#pragma unroll
        for (int j = 0; j < 4; ++j)
          acc[i][j] = __builtin_amdgcn_mfma_f32_16x16x32_bf16(af[i], bf[j], acc[i][j], 0, 0, 0);
    }
  }
  // C/D layout: col = lane&15, row = quad*4 + reg  (m89-verified)
#pragma unroll
  for (int i = 0; i < 4; ++i) {
    int mrow = m0 + wm + i * 16 + quad * 4;
#pragma unroll
    for (int j = 0; j < 4; ++j) {
      int ncol = n0 + wn + j * 16 + lm;
#pragma unroll
      for (int r = 0; r < 4; ++r) {
        int m = mrow + r;
        if (MODE == 0) {
          if (m < M) Cf[(size_t)m * GATES + ncol] = acc[i][j][r] + addend[ncol];
        } else {
          float v = acc[i][j][r] + addend[(size_t)(m & 63) * GATES + ncol];
          Cb[(size_t)m * GATES + ncol] = __float2bfloat16(v);
        }
      }
    }
  }
}

// ---------------- persistent LSTM scan (cooperative, fence-free) -------------
// v5: NO per-step cache-maintenance ops. h goes to a FRESH slot each step
// (h_all[t+1]) via system-scope RELAXED 8B atomic stores (sc0 sc1: bypass
// L1/L2, land at the Infinity Cache). Flags/gen are system-scope relaxed too.
// Ordering: producer s_waitcnt(0) between h stores and flag store; consumers
// only touch a slot's lines after the global barrier, so their cached loads
// can never see a stale L2 copy (lines never previously accessed). No
// buffer_wbl2 / buffer_inv per step — the suspected fixed ~30 us/step cost.
__global__ __launch_bounds__(256, 1) void k_scan(
    const float* __restrict__ Whh, const __hip_bfloat16* __restrict__ xg,
    const float* __restrict__ state_in, __hip_bfloat16* __restrict__ h_all,
    float* __restrict__ out_hs, float* __restrict__ out_hn, float* __restrict__ out_cn,
    unsigned* __restrict__ bar) {
  __shared__ __hip_bfloat16 Wl[16 * 1032];   // 16 slice rows [i4,f4,g4,o4], +8 pad
  __shared__ float gl[64 * 17];              // 64 batches x 16 slice cols (+1 pad)
  __shared__ unsigned long long hpack[BATCH]; // packed 4xbf16 per batch (this WG)
  __shared__ unsigned sdep;                   // polled-gen dependency broadcast
  const int tid = threadIdx.x;
  const int wg = blockIdx.x;
  const int u0 = wg * UPW;
  // W_hh slice -> LDS bf16 (once; reused for all 128 steps)
  for (int e = tid; e < 16 * 128; e += 256) {
    int j = e >> 7;
    int ko = (e & 127) << 3;
    int gate = j >> 2, uu = j & 3;
    const float* src = Whh + (size_t)(gate * HID + u0 + uu) * HID + ko;
    float4 f0 = *(const float4*)(src);
    float4 f1 = *(const float4*)(src + 4);
    union { bf16x8 v; short s[8]; } o;
    o.s[0]=f2bf_s(f0.x); o.s[1]=f2bf_s(f0.y); o.s[2]=f2bf_s(f0.z); o.s[3]=f2bf_s(f0.w);
    o.s[4]=f2bf_s(f1.x); o.s[5]=f2bf_s(f1.y); o.s[6]=f2bf_s(f1.z); o.s[7]=f2bf_s(f1.w);
    *(bf16x8*)(&Wl[j * 1032 + ko]) = o.v;
  }
  const int b = tid >> 2, u = tid & 3;       // this thread's (batch, unit) item
  float c = state_in[b * HID + u0 + u];      // c-state lives in a register
  const int w = tid >> 6, lane = tid & 63;
  const int lm = lane & 15, quad = lane >> 4;
  const int m0 = w * 16;                     // wave's batch tile
  unsigned* flags = bar;                     // flags[wg*FSTR]
  unsigned* gen = bar + NWG * FSTR;          // gen[line*FSTR], line = wg & 31
  if (tid == 0) sdep = 0;
  // xg for t=0 (software-pipelined: t+1 loads issue before each grid barrier)
  const __hip_bfloat16* xgp0 = xg + (size_t)b * GATES + u0 + u;
  float xi  = __bfloat162float(xgp0[0]);
  float xf  = __bfloat162float(xgp0[1024]);
  float xgg = __bfloat162float(xgp0[2048]);
  float xo  = __bfloat162float(xgp0[3072]);
  unsigned dep = 0;                          // data-dep on polled gen (always 0)
  __syncthreads();
  for (int t = 0; t < L_SEQ; ++t) {
    // fresh slots: read h_all[t], write h_all[t+1]
    const __hip_bfloat16* hsrc = h_all + ((size_t)t + dep) * (BATCH * HID);
    // A (= h) fragments: force 32 outstanding 16B loads per lane
    const bf16x8* arow = (const bf16x8*)(hsrc + (m0 + lm) * HID + quad * 8);
    bf16x8 areg[32];
#pragma unroll
    for (int kq = 0; kq < 32; ++kq) areg[kq] = arow[kq * 4];
    __builtin_amdgcn_sched_barrier(0);       // loads stay ABOVE all MFMAs
    f32x4 acc = {0.f, 0.f, 0.f, 0.f};
#pragma unroll
    for (int kq = 0; kq < 32; ++kq) {
      bf16x8 bfrag = *(const bf16x8*)(&Wl[lm * 1032 + kq * 32 + quad * 8]);
      acc = __builtin_amdgcn_mfma_f32_16x16x32_bf16(areg[kq], bfrag, acc, 0, 0, 0);
    }
#pragma unroll
    for (int r = 0; r < 4; ++r) gl[(m0 + quad * 4 + r) * 17 + lm] = acc[r];
    __syncthreads();
    float gi = gl[b * 17 + u]      + xi;
    float gf = gl[b * 17 + 4 + u]  + xf;
    float gg = gl[b * 17 + 8 + u]  + xgg;
    float go = gl[b * 17 + 12 + u] + xo;
    float iv = sigm(gi), fv = sigm(gf), ov = sigm(go), gv = tanh_f(gg);
    c = fv * c + iv * gv;
    float h = ov * tanh_f(c);
    __builtin_nontemporal_store(h, &out_hs[((size_t)t * BATCH + b) * HID + u0 + u]);
    // pack this WG's 4 units per batch into u64 for a single bypass store
    ((unsigned short*)hpack)[b * 4 + u] = (unsigned short)f2bf_s(h);
    if (t == L_SEQ - 1) {
      __builtin_nontemporal_store(h, &out_hn[(size_t)b * HID + u0 + u]);
      __builtin_nontemporal_store(c, &out_cn[(size_t)b * HID + u0 + u]);
    } else {
      // prefetch xg for t+1 (cached; stays warm — no inv anymore)
      const __hip_bfloat16* xgp = xg + ((size_t)(t + 1) * BATCH + b) * GATES + u0 + u;
      float nxi  = __bfloat162float(xgp[0]);
      float nxf  = __bfloat162float(xgp[1024]);
      float nxgg = __bfloat162float(xgp[2048]);
      float nxo  = __bfloat162float(xgp[3072]);
      __syncthreads();                       // hpack complete
      // h -> fresh slot via system-scope relaxed 8B stores (bypass L2 -> IC)
      unsigned long long* hdst64 =
          (unsigned long long*)(h_all + ((size_t)(t + 1)) * (BATCH * HID));
      if (tid < BATCH) {
        __hip_atomic_store(&hdst64[(tid * HID + u0) >> 2], hpack[tid],
                           __ATOMIC_RELAXED, __HIP_MEMORY_SCOPE_SYSTEM);
      }
      unsigned target = (unsigned)(t + 1);
      __builtin_amdgcn_s_waitcnt(0);         // h stores acked at IC before flag
      if (wg == 0) {
        if (tid > 0 && tid < NWG) {
          while (__hip_atomic_load(&flags[tid * FSTR], __ATOMIC_RELAXED,
                                   __HIP_MEMORY_SCOPE_SYSTEM) < target)
            __builtin_amdgcn_s_sleep(1);
        }
        __syncthreads();
        if (tid < 32) {
          __hip_atomic_store(&gen[tid * FSTR], target, __ATOMIC_RELAXED,
                             __HIP_MEMORY_SCOPE_SYSTEM);
        }
        dep = 0;                             // WG0 ordered by its own polls
      } else {
        if (tid == 0) {
          __hip_atomic_store(&flags[wg * FSTR], target, __ATOMIC_RELAXED,
                             __HIP_MEMORY_SCOPE_SYSTEM);
          unsigned g;
          do {
            g = __hip_atomic_load(&gen[(wg & 31) * FSTR], __ATOMIC_RELAXED,
                                  __HIP_MEMORY_SCOPE_SYSTEM);
            if (g < target) __builtin_amdgcn_s_sleep(1);
          } while (g < target);
          sdep = g >> 20;                    // always 0; carries data dep
        }
        __syncthreads();
        dep = sdep;                          // all threads' hsrc depends on poll
      }
      xi = nxi; xf = nxf; xgg = nxgg; xo = nxo;
    }
  }
}

extern "C" void kernel_launch(void* const* d_in, const int* in_sizes, int n_in,
                              void* d_out, int out_size, void* d_ws, size_t ws_size,
                              hipStream_t stream) {
  const float* x      = (const float*)d_in[0];
  const int*   pa     = (const int*)d_in[1];
  // d_in[2] = mask (unused by reference)
  const float* hidden = (const float*)d_in[3];
  const float* state  = (const float*)d_in[4];
  const float* remb   = (const float*)d_in[5];
  const float* temb   = (const float*)d_in[6];
  const float* Wih    = (const float*)d_in[7];
  const float* Whh    = (const float*)d_in[8];
  const float* bih    = (const float*)d_in[9];
  const float* bhh    = (const float*)d_in[10];

  char* ws = (char*)d_ws;
  size_t off = 0;
  auto take = [&](size_t bytes) { char* p = ws + off; off += (bytes + 255) & ~(size_t)255; return p; };
  unsigned* bar         = (unsigned*)take(16384 * 4);  // padded flags + gen lines
  __hip_bfloat16* h_all = (__hip_bfloat16*)take((size_t)L_SEQ * BATCH * HID * 2); // 16 MB fresh slots
  __hip_bfloat16* x_bf  = (__hip_bfloat16*)take((size_t)BATCH * 512 * 2);
  float* bias2          = (float*)take((size_t)GATES * 4);
  __hip_bfloat16* Wx    = (__hip_bfloat16*)take((size_t)GATES * 512 * 2);
  __hip_bfloat16* Wa    = (__hip_bfloat16*)take((size_t)GATES * 512 * 2);
  __hip_bfloat16* act   = (__hip_bfloat16*)take((size_t)8192 * 512 * 2);
  float* y0             = (float*)take((size_t)BATCH * GATES * 4);
  __hip_bfloat16* xg    = (__hip_bfloat16*)take((size_t)8192 * GATES * 2); // ~97 MB total

  float* out_hs = (float*)d_out;
  float* out_hn = out_hs + (size_t)L_SEQ * BATCH * HID;
  float* out_cn = out_hn + (size_t)BATCH * HID;

  hipLaunchKernelGGL(k_init, dim3(256), dim3(256), 0, stream, hidden, x, bih, bhh, h_all, x_bf, bias2, bar);
  hipLaunchKernelGGL(k_wsplit, dim3(2048), dim3(256), 0, stream, Wih, Wx, Wa);
  hipLaunchKernelGGL(k_act, dim3(8192), dim3(64), 0, stream, pa, remb, temb, act);
  hipLaunchKernelGGL((k_gemm<0>), dim3(32, 1), dim3(256), 0, stream,
                     x_bf, Wx, bias2, y0, (__hip_bfloat16*)nullptr, 64);
  hipLaunchKernelGGL((k_gemm<1>), dim3(32, 64), dim3(256), 0, stream,
                     act, Wa, y0, (float*)nullptr, xg, 8192);
  void* args[] = { (void*)&Whh, (void*)&xg, (void*)&state, (void*)&h_all,
                   (void*)&out_hs, (void*)&out_hn, (void*)&out_cn, (void*)&bar };
  (void)hipLaunchCooperativeKernel((void*)k_scan, dim3(NWG), dim3(256), args, 0, stream);
}